// Round 6
// baseline (12995.837 us; speedup 1.0000x reference)
//
#include <hip/hip_runtime.h>
#include <hip/hip_bf16.h>

// ---------------- helpers ----------------
__device__ inline float fsig(float x) { return 1.0f / (1.0f + __expf(-x)); }
__device__ inline float ftanh(float x) {
    float ax = fabsf(x);
    float e = __expf(-2.0f * ax);
    float r = (1.0f - e) / (1.0f + e);
    return x >= 0.0f ? r : -r;
}
__device__ inline float felu(float x) { return x > 0.0f ? x : expm1f(x); }

__device__ inline unsigned short f16bits(float a) {
    return __builtin_bit_cast(unsigned short, (_Float16)a);
}

typedef _Float16 f16x8 __attribute__((ext_vector_type(8)));
typedef float f32x4 __attribute__((ext_vector_type(4)));

// ---------------- conv: one block per (t, oy) output row ----------------
template <int CIN, int W, int OW, int PAD>
__global__ __launch_bounds__(256) void conv_row(const float* __restrict__ in,
                                                const float* __restrict__ wg,
                                                const float* __restrict__ bias,
                                                float* __restrict__ out) {
    constexpr int WP = W + 2;
    __shared__ float in_s[3 * WP * CIN];
    constexpr int NQ = 3 * WP * CIN / 4;
    constexpr int QROW = WP * CIN / 4;
    const int tid = threadIdx.x;
    const int oy = blockIdx.x;
    const int t = blockIdx.y;
    const int co = tid & 31;

    for (int q = tid; q < NQ; q += 256) {
        int ky = q / QROW;
        int rem = q - ky * QROW;
        int col = rem / (CIN / 4);
        int c4 = rem - col * (CIN / 4);
        int iy = 2 * oy - PAD + ky;
        int ix = col - 1;
        float4 v = make_float4(0.f, 0.f, 0.f, 0.f);
        if (iy >= 0 && iy < W && ix >= 0 && ix < W)
            v = *(const float4*)&in[(((size_t)t * W + iy) * W + ix) * CIN + c4 * 4];
        *(float4*)&in_s[q * 4] = v;
    }

    if constexpr (CIN == 4) {
        float wr[9][4];
#pragma unroll
        for (int tap = 0; tap < 9; ++tap)
#pragma unroll
            for (int j = 0; j < 4; ++j) wr[tap][j] = wg[(tap * 4 + j) * 32 + co];
        __syncthreads();

        const int g = tid >> 5;
        constexpr int NOX = (OW + 7) / 8;
        float acc[NOX];
#pragma unroll
        for (int m = 0; m < NOX; ++m) acc[m] = 0.f;
#pragma unroll
        for (int ky = 0; ky < 3; ++ky)
#pragma unroll
            for (int kx = 0; kx < 3; ++kx) {
                float w0 = wr[ky * 3 + kx][0], w1 = wr[ky * 3 + kx][1];
                float w2 = wr[ky * 3 + kx][2], w3 = wr[ky * 3 + kx][3];
#pragma unroll
                for (int m = 0; m < NOX; ++m) {
                    int ox = g + 8 * m;
                    if (ox < OW) {
                        int cs = 2 * ox + kx - PAD + 1;
                        float4 xi = *(const float4*)&in_s[(ky * WP + cs) * 4];
                        acc[m] += xi.x * w0 + xi.y * w1 + xi.z * w2 + xi.w * w3;
                    }
                }
            }
        float b = bias[co];
#pragma unroll
        for (int m = 0; m < NOX; ++m) {
            int ox = g + 8 * m;
            if (ox < OW)
                out[(((size_t)t * OW + oy) * OW + ox) * 32 + co] = felu(acc[m] + b);
        }
    } else {
        const int cig = tid >> 5;
        float wr[9][4];
#pragma unroll
        for (int tap = 0; tap < 9; ++tap)
#pragma unroll
            for (int j = 0; j < 4; ++j) wr[tap][j] = wg[(tap * 32 + cig * 4 + j) * 32 + co];
        __syncthreads();

        float acc[OW];
#pragma unroll
        for (int ox = 0; ox < OW; ++ox) acc[ox] = 0.f;
#pragma unroll
        for (int ky = 0; ky < 3; ++ky)
#pragma unroll
            for (int kx = 0; kx < 3; ++kx) {
                const float* ip = &in_s[(ky * WP) * 32 + cig * 4];
                float w0 = wr[ky * 3 + kx][0], w1 = wr[ky * 3 + kx][1];
                float w2 = wr[ky * 3 + kx][2], w3 = wr[ky * 3 + kx][3];
#pragma unroll
                for (int ox = 0; ox < OW; ++ox) {
                    int cs = 2 * ox + kx - PAD + 1;
                    float4 xi = *(const float4*)&ip[cs * 32];
                    acc[ox] += xi.x * w0 + xi.y * w1 + xi.z * w2 + xi.w * w3;
                }
            }
        __shared__ float zs[8][OW * 32];
#pragma unroll
        for (int ox = 0; ox < OW; ++ox) zs[cig][ox * 32 + co] = acc[ox];
        __syncthreads();
        for (int idx = tid; idx < OW * 32; idx += 256) {
            float s = zs[0][idx] + zs[1][idx] + zs[2][idx] + zs[3][idx] +
                      zs[4][idx] + zs[5][idx] + zs[6][idx] + zs[7][idx] + bias[idx & 31];
            out[(((size_t)t * OW + oy) * OW) * 32 + idx] = felu(s);
        }
    }
}

// ---------------- xpart GEMM ----------------
__global__ void gemm_kernel(const float* __restrict__ A, const float* __restrict__ Wx,
                            const float* __restrict__ bias, float* __restrict__ C) {
    __shared__ float As[32][64];
    __shared__ float Bs[32][64];
    const int bn = blockIdx.x, bm = blockIdx.y;
    const int tx = threadIdx.x, ty = threadIdx.y;
    const int tid = ty * 16 + tx;
    float acc[4][4] = {};
    for (int k0 = 0; k0 < 1152; k0 += 32) {
        {
            int r = tid >> 3;
            int c = (tid & 7) * 4;
            float4 a0 = *(const float4*)&A[(size_t)(bm * 64 + r) * 1152 + k0 + c];
            float4 a1 = *(const float4*)&A[(size_t)(bm * 64 + r + 32) * 1152 + k0 + c];
            As[c + 0][r] = a0.x; As[c + 1][r] = a0.y; As[c + 2][r] = a0.z; As[c + 3][r] = a0.w;
            As[c + 0][r + 32] = a1.x; As[c + 1][r + 32] = a1.y; As[c + 2][r + 32] = a1.z; As[c + 3][r + 32] = a1.w;
            int rb = tid >> 4;
            int cb = (tid & 15) * 4;
            *(float4*)&Bs[rb][cb] = *(const float4*)&Wx[(size_t)(k0 + rb) * 1024 + bn * 64 + cb];
            *(float4*)&Bs[rb + 16][cb] = *(const float4*)&Wx[(size_t)(k0 + rb + 16) * 1024 + bn * 64 + cb];
        }
        __syncthreads();
#pragma unroll
        for (int kk = 0; kk < 32; ++kk) {
            float4 a = *(float4*)&As[kk][ty * 4];
            float4 b = *(float4*)&Bs[kk][tx * 4];
            acc[0][0] += a.x * b.x; acc[0][1] += a.x * b.y; acc[0][2] += a.x * b.z; acc[0][3] += a.x * b.w;
            acc[1][0] += a.y * b.x; acc[1][1] += a.y * b.y; acc[1][2] += a.y * b.z; acc[1][3] += a.y * b.w;
            acc[2][0] += a.z * b.x; acc[2][1] += a.z * b.y; acc[2][2] += a.z * b.z; acc[2][3] += a.z * b.w;
            acc[3][0] += a.w * b.x; acc[3][1] += a.w * b.y; acc[3][2] += a.w * b.z; acc[3][3] += a.w * b.w;
        }
        __syncthreads();
    }
#pragma unroll
    for (int i = 0; i < 4; ++i) {
        int row = bm * 64 + ty * 4 + i;
#pragma unroll
        for (int j = 0; j < 4; ++j) {
            int col = bn * 64 + tx * 4 + j;
            C[(size_t)row * 1024 + col] = acc[i][j] + bias[col];
        }
    }
}

// ---------------- LSTM: ONE workgroup, MFMA recurrence ----------------
// 16 waves; wave w owns output cols [64w, 64w+64). Per wave: 32 persistent B-frags
// (8 k-tiles x 4 n-tiles, f16, 128 regs -> AGPR-resident; MFMA reads AGPR natively).
// A = h broadcast to all 16 rows (every lane's A-frag = same 16B h-slice for its
// k-group) -> all C rows equal z. A and B loaded with the SAME (lane,reg)->k map,
// so correctness is independent of the hardware's exact k layout (bijection arg).
// Lane l of wave w ends up owning z[64w+l] (fragment nt=l>>4, col slot l&15).
// Raw s_barrier + lgkmcnt-only drains keep xpart prefetch / hs_out stores in flight.
__global__ __launch_bounds__(1024) void lstm_mfma_kernel(const float* __restrict__ lstm_w,
                                                         const float* __restrict__ xpart,
                                                         const float* __restrict__ c_in,
                                                         const float* __restrict__ h_in,
                                                         float* __restrict__ hs_out) {
    __shared__ __align__(16) unsigned short hbuf[2][256];  // h as f16, double-buffered
    __shared__ float zsm[1024];

    const int j = threadIdx.x;
    const int w = j >> 6;       // wave 0..15
    const int l = j & 63;
    const int G = l >> 4;       // k-subgroup 0..3
    const int n16 = l & 15;

    // persistent B fragments: bf[kt][nt], lane holds W[1152 + kt*32 + G*8 + jj][64w + nt*16 + n16]
    f16x8 bf[8][4];
#pragma unroll
    for (int kt = 0; kt < 8; ++kt)
#pragma unroll
        for (int nt = 0; nt < 4; ++nt) {
            const int col = (w << 6) + (nt << 4) + n16;
            f16x8 v;
#pragma unroll
            for (int jj = 0; jj < 8; ++jj) {
                int k = kt * 32 + G * 8 + jj;
                v[jj] = (_Float16)lstm_w[(size_t)(1152 + k) * 1024 + col];
            }
            bf[kt][nt] = v;
        }

    float c_state = c_in[j & 255];      // every thread keeps a copy of its unit's cell state
    if (j < 256) hbuf[0][j] = f16bits(h_in[j]);
    __syncthreads();

    float xp = xpart[j];                // xpart[t=0][col=j]
    for (int t = 0; t < 2048; ++t) {
        const int cur = t & 1;
        const char* hb = reinterpret_cast<const char*>(&hbuf[cur][0]);

        f32x4 acc0 = {0.f, 0.f, 0.f, 0.f};
        f32x4 acc1 = {0.f, 0.f, 0.f, 0.f};
        f32x4 acc2 = {0.f, 0.f, 0.f, 0.f};
        f32x4 acc3 = {0.f, 0.f, 0.f, 0.f};
#pragma unroll
        for (int kt = 0; kt < 8; ++kt) {
            f16x8 a = *reinterpret_cast<const f16x8*>(hb + (kt << 6) + (G << 4));
            acc0 = __builtin_amdgcn_mfma_f32_16x16x32_f16(a, bf[kt][0], acc0, 0, 0, 0);
            acc1 = __builtin_amdgcn_mfma_f32_16x16x32_f16(a, bf[kt][1], acc1, 0, 0, 0);
            acc2 = __builtin_amdgcn_mfma_f32_16x16x32_f16(a, bf[kt][2], acc2, 0, 0, 0);
            acc3 = __builtin_amdgcn_mfma_f32_16x16x32_f16(a, bf[kt][3], acc3, 0, 0, 0);
        }
        // lane l owns col 64w + l = 64w + G*16 + n16 -> fragment index nt == G
        float zv = (G == 0) ? acc0[0] : (G == 1) ? acc1[0] : (G == 2) ? acc2[0] : acc3[0];
        zsm[j] = zv + xp;

        float xpn = (t + 1 < 2048) ? xpart[(size_t)(t + 1) * 1024 + j] : 0.f;

        asm volatile("s_waitcnt lgkmcnt(0)\n\ts_barrier" ::: "memory");

        const int u = j & 255;          // unit, computed redundantly by 4 threads
        float zi = zsm[u];
        float zg = zsm[256 + u];
        float zf = zsm[512 + u];
        float zo = zsm[768 + u];
        c_state = c_state * fsig(zf + 1.0f) + fsig(zi) * ftanh(zg);
        float h = ftanh(c_state) * fsig(zo);
        if (j < 256) {
            hs_out[(size_t)t * 256 + j] = h;
            hbuf[cur ^ 1][j] = f16bits(h);
        }

        asm volatile("s_waitcnt lgkmcnt(0)\n\ts_barrier" ::: "memory");
        xp = xpn;
    }
}

// ---------------- logits ----------------
__global__ void logits_kernel(const float* __restrict__ hs, const float* __restrict__ fc_w,
                              const float* __restrict__ fc_b, float* __restrict__ out) {
    int idx = blockIdx.x * 256 + threadIdx.x;
    if (idx >= 2048 * 18) return;
    int t = idx / 18, n = idx % 18;
    float acc = fc_b[n];
    const float* hrow = hs + (size_t)t * 256;
#pragma unroll 4
    for (int k = 0; k < 256; ++k) acc += hrow[k] * fc_w[k * 18 + n];
    out[idx] = acc;
}

// ---------------- launch ----------------
extern "C" void kernel_launch(void* const* d_in, const int* in_sizes, int n_in,
                              void* d_out, int out_size, void* d_ws, size_t ws_size,
                              hipStream_t stream) {
    const float* x   = (const float*)d_in[0];
    const float* w0  = (const float*)d_in[1];
    const float* b0  = (const float*)d_in[2];
    const float* w1  = (const float*)d_in[3];
    const float* b1  = (const float*)d_in[4];
    const float* w2  = (const float*)d_in[5];
    const float* b2  = (const float*)d_in[6];
    const float* w3  = (const float*)d_in[7];
    const float* b3  = (const float*)d_in[8];
    const float* lw  = (const float*)d_in[9];
    const float* lb  = (const float*)d_in[10];
    const float* fcw = (const float*)d_in[11];
    const float* fcb = (const float*)d_in[12];
    const float* cin = (const float*)d_in[13];
    const float* hin = (const float*)d_in[14];

    float* outp = (float*)d_out;
    float* hs_out = outp + 2048 * 18;

    const size_t PERT = 56448 + 14112 + 3872;
    const size_t FIXED = (size_t)2048 * 1152 + (size_t)2048 * 1024;

    int C = 128;
    const int cands[4] = {2048, 1024, 512, 256};
    for (int i = 0; i < 4; ++i) {
        if ((FIXED + (size_t)cands[i] * PERT) * 4 <= ws_size) { C = cands[i]; break; }
    }

    float* ws    = (float*)d_ws;
    float* c0buf = ws;
    float* c1buf = c0buf + (size_t)C * 56448;
    float* c2buf = c1buf + (size_t)C * 14112;
    float* feats = c2buf + (size_t)C * 3872;
    float* xpart = feats + (size_t)2048 * 1152;

    for (int t0 = 0; t0 < 2048; t0 += C) {
        const float* xin = x + (size_t)t0 * 84 * 84 * 4;
        conv_row<4, 84, 42, 0><<<dim3(42, C), 256, 0, stream>>>(xin, w0, b0, c0buf);
        conv_row<32, 42, 21, 0><<<dim3(21, C), 256, 0, stream>>>(c0buf, w1, b1, c1buf);
        conv_row<32, 21, 11, 1><<<dim3(11, C), 256, 0, stream>>>(c1buf, w2, b2, c2buf);
        conv_row<32, 11, 6, 1><<<dim3(6, C), 256, 0, stream>>>(c2buf, w3, b3,
                                                               feats + (size_t)t0 * 1152);
    }

    gemm_kernel<<<dim3(16, 32), dim3(16, 16), 0, stream>>>(feats, lw, lb, xpart);
    lstm_mfma_kernel<<<1, 1024, 0, stream>>>(lw, xpart, cin, hin, hs_out);
    logits_kernel<<<144, 256, 0, stream>>>(hs_out, fcw, fcb, outp);
}

// Round 7
// 4672.012 us; speedup vs baseline: 2.7816x; 2.7816x over previous
//
#include <hip/hip_runtime.h>
#include <hip/hip_bf16.h>

// ---------------- helpers ----------------
__device__ inline float fsig(float x) { return 1.0f / (1.0f + __expf(-x)); }
__device__ inline float ftanh(float x) {
    float ax = fabsf(x);
    float e = __expf(-2.0f * ax);
    float r = (1.0f - e) / (1.0f + e);
    return x >= 0.0f ? r : -r;
}
__device__ inline float felu(float x) { return x > 0.0f ? x : expm1f(x); }

typedef _Float16 h2_t __attribute__((ext_vector_type(2)));

__device__ inline unsigned int packh2(float a, float b) {
    unsigned short ua = __builtin_bit_cast(unsigned short, (_Float16)a);
    unsigned short ub = __builtin_bit_cast(unsigned short, (_Float16)b);
    return (unsigned int)ua | ((unsigned int)ub << 16);
}
__device__ inline unsigned short f16bits(float a) {
    return __builtin_bit_cast(unsigned short, (_Float16)a);
}

__device__ inline float dot2acc(unsigned int w, unsigned int h, float acc) {
#if __has_builtin(__builtin_amdgcn_fdot2)
    return __builtin_amdgcn_fdot2(__builtin_bit_cast(h2_t, w), __builtin_bit_cast(h2_t, h), acc, false);
#else
    _Float16 wlo = __builtin_bit_cast(_Float16, (unsigned short)(w & 0xffff));
    _Float16 whi = __builtin_bit_cast(_Float16, (unsigned short)(w >> 16));
    _Float16 hlo = __builtin_bit_cast(_Float16, (unsigned short)(h & 0xffff));
    _Float16 hhi = __builtin_bit_cast(_Float16, (unsigned short)(h >> 16));
    return acc + (float)wlo * (float)hlo + (float)whi * (float)hhi;
#endif
}

// ---------------- conv: one block per (t, oy) output row ----------------
template <int CIN, int W, int OW, int PAD>
__global__ __launch_bounds__(256) void conv_row(const float* __restrict__ in,
                                                const float* __restrict__ wg,
                                                const float* __restrict__ bias,
                                                float* __restrict__ out) {
    constexpr int WP = W + 2;
    __shared__ float in_s[3 * WP * CIN];
    constexpr int NQ = 3 * WP * CIN / 4;
    constexpr int QROW = WP * CIN / 4;
    const int tid = threadIdx.x;
    const int oy = blockIdx.x;
    const int t = blockIdx.y;
    const int co = tid & 31;

    for (int q = tid; q < NQ; q += 256) {
        int ky = q / QROW;
        int rem = q - ky * QROW;
        int col = rem / (CIN / 4);
        int c4 = rem - col * (CIN / 4);
        int iy = 2 * oy - PAD + ky;
        int ix = col - 1;
        float4 v = make_float4(0.f, 0.f, 0.f, 0.f);
        if (iy >= 0 && iy < W && ix >= 0 && ix < W)
            v = *(const float4*)&in[(((size_t)t * W + iy) * W + ix) * CIN + c4 * 4];
        *(float4*)&in_s[q * 4] = v;
    }

    if constexpr (CIN == 4) {
        float wr[9][4];
#pragma unroll
        for (int tap = 0; tap < 9; ++tap)
#pragma unroll
            for (int j = 0; j < 4; ++j) wr[tap][j] = wg[(tap * 4 + j) * 32 + co];
        __syncthreads();

        const int g = tid >> 5;
        constexpr int NOX = (OW + 7) / 8;
        float acc[NOX];
#pragma unroll
        for (int m = 0; m < NOX; ++m) acc[m] = 0.f;
#pragma unroll
        for (int ky = 0; ky < 3; ++ky)
#pragma unroll
            for (int kx = 0; kx < 3; ++kx) {
                float w0 = wr[ky * 3 + kx][0], w1 = wr[ky * 3 + kx][1];
                float w2 = wr[ky * 3 + kx][2], w3 = wr[ky * 3 + kx][3];
#pragma unroll
                for (int m = 0; m < NOX; ++m) {
                    int ox = g + 8 * m;
                    if (ox < OW) {
                        int cs = 2 * ox + kx - PAD + 1;
                        float4 xi = *(const float4*)&in_s[(ky * WP + cs) * 4];
                        acc[m] += xi.x * w0 + xi.y * w1 + xi.z * w2 + xi.w * w3;
                    }
                }
            }
        float b = bias[co];
#pragma unroll
        for (int m = 0; m < NOX; ++m) {
            int ox = g + 8 * m;
            if (ox < OW)
                out[(((size_t)t * OW + oy) * OW + ox) * 32 + co] = felu(acc[m] + b);
        }
    } else {
        const int cig = tid >> 5;
        float wr[9][4];
#pragma unroll
        for (int tap = 0; tap < 9; ++tap)
#pragma unroll
            for (int j = 0; j < 4; ++j) wr[tap][j] = wg[(tap * 32 + cig * 4 + j) * 32 + co];
        __syncthreads();

        float acc[OW];
#pragma unroll
        for (int ox = 0; ox < OW; ++ox) acc[ox] = 0.f;
#pragma unroll
        for (int ky = 0; ky < 3; ++ky)
#pragma unroll
            for (int kx = 0; kx < 3; ++kx) {
                const float* ip = &in_s[(ky * WP) * 32 + cig * 4];
                float w0 = wr[ky * 3 + kx][0], w1 = wr[ky * 3 + kx][1];
                float w2 = wr[ky * 3 + kx][2], w3 = wr[ky * 3 + kx][3];
#pragma unroll
                for (int ox = 0; ox < OW; ++ox) {
                    int cs = 2 * ox + kx - PAD + 1;
                    float4 xi = *(const float4*)&ip[cs * 32];
                    acc[ox] += xi.x * w0 + xi.y * w1 + xi.z * w2 + xi.w * w3;
                }
            }
        __shared__ float zs[8][OW * 32];
#pragma unroll
        for (int ox = 0; ox < OW; ++ox) zs[cig][ox * 32 + co] = acc[ox];
        __syncthreads();
        for (int idx = tid; idx < OW * 32; idx += 256) {
            float s = zs[0][idx] + zs[1][idx] + zs[2][idx] + zs[3][idx] +
                      zs[4][idx] + zs[5][idx] + zs[6][idx] + zs[7][idx] + bias[idx & 31];
            out[(((size_t)t * OW + oy) * OW) * 32 + idx] = felu(s);
        }
    }
}

// ---------------- xpart GEMM ----------------
__global__ void gemm_kernel(const float* __restrict__ A, const float* __restrict__ Wx,
                            const float* __restrict__ bias, float* __restrict__ C) {
    __shared__ float As[32][64];
    __shared__ float Bs[32][64];
    const int bn = blockIdx.x, bm = blockIdx.y;
    const int tx = threadIdx.x, ty = threadIdx.y;
    const int tid = ty * 16 + tx;
    float acc[4][4] = {};
    for (int k0 = 0; k0 < 1152; k0 += 32) {
        {
            int r = tid >> 3;
            int c = (tid & 7) * 4;
            float4 a0 = *(const float4*)&A[(size_t)(bm * 64 + r) * 1152 + k0 + c];
            float4 a1 = *(const float4*)&A[(size_t)(bm * 64 + r + 32) * 1152 + k0 + c];
            As[c + 0][r] = a0.x; As[c + 1][r] = a0.y; As[c + 2][r] = a0.z; As[c + 3][r] = a0.w;
            As[c + 0][r + 32] = a1.x; As[c + 1][r + 32] = a1.y; As[c + 2][r + 32] = a1.z; As[c + 3][r + 32] = a1.w;
            int rb = tid >> 4;
            int cb = (tid & 15) * 4;
            *(float4*)&Bs[rb][cb] = *(const float4*)&Wx[(size_t)(k0 + rb) * 1024 + bn * 64 + cb];
            *(float4*)&Bs[rb + 16][cb] = *(const float4*)&Wx[(size_t)(k0 + rb + 16) * 1024 + bn * 64 + cb];
        }
        __syncthreads();
#pragma unroll
        for (int kk = 0; kk < 32; ++kk) {
            float4 a = *(float4*)&As[kk][ty * 4];
            float4 b = *(float4*)&Bs[kk][tx * 4];
            acc[0][0] += a.x * b.x; acc[0][1] += a.x * b.y; acc[0][2] += a.x * b.z; acc[0][3] += a.x * b.w;
            acc[1][0] += a.y * b.x; acc[1][1] += a.y * b.y; acc[1][2] += a.y * b.z; acc[1][3] += a.y * b.w;
            acc[2][0] += a.z * b.x; acc[2][1] += a.z * b.y; acc[2][2] += a.z * b.z; acc[2][3] += a.z * b.w;
            acc[3][0] += a.w * b.x; acc[3][1] += a.w * b.y; acc[3][2] += a.w * b.z; acc[3][3] += a.w * b.w;
        }
        __syncthreads();
    }
#pragma unroll
    for (int i = 0; i < 4; ++i) {
        int row = bm * 64 + ty * 4 + i;
#pragma unroll
        for (int j = 0; j < 4; ++j) {
            int col = bn * 64 + tx * 4 + j;
            C[(size_t)row * 1024 + col] = acc[i][j] + bias[col];
        }
    }
}

// ---------------- LSTM: ONE workgroup, 8 waves, 2 cols/thread ----------------
// Thread tid owns gate-columns c0=tid and c1=tid+512. Per column 128 f16 weight
// pairs: pairs 0..31 in LDS ([col][36-uint stride] rows: 16B-aligned, bank-start
// 4*lane mod 32 -> even 32-bank coverage, floor-rate ds_read_b128), pairs 32..127
// in AGPRs. h broadcast via 32 b128 reads/thread (one read feeds BOTH columns).
// lgkm-only barriers keep the xpart prefetch + hs_out stores in flight (round-6-
// proven pattern); compiler inserts the vmcnt wait at xp's use site.
__global__ __launch_bounds__(512, 2) void lstm4_kernel(const float* __restrict__ lstm_w,
                                                       const float* __restrict__ xpart,
                                                       const float* __restrict__ c_in,
                                                       const float* __restrict__ h_in,
                                                       float* __restrict__ hs_out) {
    __shared__ __align__(16) unsigned int wlds[1024][36];   // 32 pairs used, stride 36
    __shared__ float zsm[1024];
    __shared__ __align__(16) unsigned short hbuf[2][256];   // h as f16, double-buffered

    const int tid = threadIdx.x;
    const int c0 = tid;
    const int c1 = tid + 512;

    // stage LDS pairs 0..31 (k = 0..63) for both columns
    for (int p = 0; p < 32; ++p) {
        wlds[c0][p] = packh2(lstm_w[(size_t)(1152 + 2 * p) * 1024 + c0],
                             lstm_w[(size_t)(1152 + 2 * p + 1) * 1024 + c0]);
        wlds[c1][p] = packh2(lstm_w[(size_t)(1152 + 2 * p) * 1024 + c1],
                             lstm_w[(size_t)(1152 + 2 * p + 1) * 1024 + c1]);
    }
    // AGPR pairs 32..127 (k = 64..255)
    unsigned int wrA[96], wrB[96];
#pragma unroll
    for (int r = 0; r < 96; ++r) {
        int p = 32 + r;
        wrA[r] = packh2(lstm_w[(size_t)(1152 + 2 * p) * 1024 + c0],
                        lstm_w[(size_t)(1152 + 2 * p + 1) * 1024 + c0]);
        wrB[r] = packh2(lstm_w[(size_t)(1152 + 2 * p) * 1024 + c1],
                        lstm_w[(size_t)(1152 + 2 * p + 1) * 1024 + c1]);
    }

    float c_state = 0.0f;
    if (tid < 256) {
        c_state = c_in[tid];
        hbuf[0][tid] = f16bits(h_in[tid]);
    }
    __syncthreads();

    float xpA = xpart[c0];
    float xpB = xpart[c1];
    for (int t = 0; t < 2048; ++t) {
        const int cur = t & 1;
        const uint4* hq = reinterpret_cast<const uint4*>(&hbuf[cur][0]);

        float a0 = 0.f, a1 = 0.f, a2 = 0.f, a3 = 0.f;
        float b0 = 0.f, b1 = 0.f, b2 = 0.f, b3 = 0.f;
#pragma unroll
        for (int c = 0; c < 8; ++c) {            // pairs 4c..4c+3 from LDS
            uint4 h4 = hq[c];
            uint4 wa = *reinterpret_cast<const uint4*>(&wlds[c0][4 * c]);
            uint4 wb = *reinterpret_cast<const uint4*>(&wlds[c1][4 * c]);
            a0 = dot2acc(wa.x, h4.x, a0); a1 = dot2acc(wa.y, h4.y, a1);
            a2 = dot2acc(wa.z, h4.z, a2); a3 = dot2acc(wa.w, h4.w, a3);
            b0 = dot2acc(wb.x, h4.x, b0); b1 = dot2acc(wb.y, h4.y, b1);
            b2 = dot2acc(wb.z, h4.z, b2); b3 = dot2acc(wb.w, h4.w, b3);
        }
#pragma unroll
        for (int c = 8; c < 32; ++c) {           // pairs 4c..4c+3 from AGPRs
            uint4 h4 = hq[c];
            const int r = 4 * c - 32;
            a0 = dot2acc(wrA[r + 0], h4.x, a0); a1 = dot2acc(wrA[r + 1], h4.y, a1);
            a2 = dot2acc(wrA[r + 2], h4.z, a2); a3 = dot2acc(wrA[r + 3], h4.w, a3);
            b0 = dot2acc(wrB[r + 0], h4.x, b0); b1 = dot2acc(wrB[r + 1], h4.y, b1);
            b2 = dot2acc(wrB[r + 2], h4.z, b2); b3 = dot2acc(wrB[r + 3], h4.w, b3);
        }
        zsm[c0] = (a0 + a1) + (a2 + a3) + xpA;
        zsm[c1] = (b0 + b1) + (b2 + b3) + xpB;

        float xpAn = 0.f, xpBn = 0.f;
        if (t + 1 < 2048) {
            xpAn = xpart[(size_t)(t + 1) * 1024 + c0];
            xpBn = xpart[(size_t)(t + 1) * 1024 + c1];
        }

        asm volatile("s_waitcnt lgkmcnt(0)\n\ts_barrier" ::: "memory");

        if (tid < 256) {
            float zi = zsm[tid];
            float zg = zsm[256 + tid];
            float zf = zsm[512 + tid];
            float zo = zsm[768 + tid];
            c_state = c_state * fsig(zf + 1.0f) + fsig(zi) * ftanh(zg);
            float h = ftanh(c_state) * fsig(zo);
            hs_out[(size_t)t * 256 + tid] = h;
            hbuf[cur ^ 1][tid] = f16bits(h);
        }

        asm volatile("s_waitcnt lgkmcnt(0)\n\ts_barrier" ::: "memory");
        xpA = xpAn;
        xpB = xpBn;
    }
}

// ---------------- logits ----------------
__global__ void logits_kernel(const float* __restrict__ hs, const float* __restrict__ fc_w,
                              const float* __restrict__ fc_b, float* __restrict__ out) {
    int idx = blockIdx.x * 256 + threadIdx.x;
    if (idx >= 2048 * 18) return;
    int t = idx / 18, n = idx % 18;
    float acc = fc_b[n];
    const float* hrow = hs + (size_t)t * 256;
#pragma unroll 4
    for (int k = 0; k < 256; ++k) acc += hrow[k] * fc_w[k * 18 + n];
    out[idx] = acc;
}

// ---------------- launch ----------------
extern "C" void kernel_launch(void* const* d_in, const int* in_sizes, int n_in,
                              void* d_out, int out_size, void* d_ws, size_t ws_size,
                              hipStream_t stream) {
    const float* x   = (const float*)d_in[0];
    const float* w0  = (const float*)d_in[1];
    const float* b0  = (const float*)d_in[2];
    const float* w1  = (const float*)d_in[3];
    const float* b1  = (const float*)d_in[4];
    const float* w2  = (const float*)d_in[5];
    const float* b2  = (const float*)d_in[6];
    const float* w3  = (const float*)d_in[7];
    const float* b3  = (const float*)d_in[8];
    const float* lw  = (const float*)d_in[9];
    const float* lb  = (const float*)d_in[10];
    const float* fcw = (const float*)d_in[11];
    const float* fcb = (const float*)d_in[12];
    const float* cin = (const float*)d_in[13];
    const float* hin = (const float*)d_in[14];

    float* outp = (float*)d_out;
    float* hs_out = outp + 2048 * 18;

    const size_t PERT = 56448 + 14112 + 3872;
    const size_t FIXED = (size_t)2048 * 1152 + (size_t)2048 * 1024;

    int C = 128;
    const int cands[4] = {2048, 1024, 512, 256};
    for (int i = 0; i < 4; ++i) {
        if ((FIXED + (size_t)cands[i] * PERT) * 4 <= ws_size) { C = cands[i]; break; }
    }

    float* ws    = (float*)d_ws;
    float* c0buf = ws;
    float* c1buf = c0buf + (size_t)C * 56448;
    float* c2buf = c1buf + (size_t)C * 14112;
    float* feats = c2buf + (size_t)C * 3872;
    float* xpart = feats + (size_t)2048 * 1152;

    for (int t0 = 0; t0 < 2048; t0 += C) {
        const float* xin = x + (size_t)t0 * 84 * 84 * 4;
        conv_row<4, 84, 42, 0><<<dim3(42, C), 256, 0, stream>>>(xin, w0, b0, c0buf);
        conv_row<32, 42, 21, 0><<<dim3(21, C), 256, 0, stream>>>(c0buf, w1, b1, c1buf);
        conv_row<32, 21, 11, 1><<<dim3(11, C), 256, 0, stream>>>(c1buf, w2, b2, c2buf);
        conv_row<32, 11, 6, 1><<<dim3(6, C), 256, 0, stream>>>(c2buf, w3, b3,
                                                               feats + (size_t)t0 * 1152);
    }

    gemm_kernel<<<dim3(16, 32), dim3(16, 16), 0, stream>>>(feats, lw, lb, xpart);
    lstm4_kernel<<<1, 512, 0, stream>>>(lw, xpart, cin, hin, hs_out);
    logits_kernel<<<144, 256, 0, stream>>>(hs_out, fcw, fcb, outp);
}